// Round 19
// baseline (76.914 us; speedup 1.0000x reference)
//
#include <hip/hip_runtime.h>
#include <math.h>

constexpr int BATCH = 256;

typedef short short8 __attribute__((ext_vector_type(8)));
typedef float f32x4 __attribute__((ext_vector_type(4)));
typedef float f32x16 __attribute__((ext_vector_type(16)));

// ---------------------------------------------------------------------------
// bf16 helpers (RNE)
// ---------------------------------------------------------------------------
__device__ __forceinline__ unsigned short f2bf(float f) {
    unsigned int u = __float_as_uint(f);
    u += 0x7FFFu + ((u >> 16) & 1u);
    return (unsigned short)(u >> 16);
}
__device__ __forceinline__ unsigned int pack2(float a, float b) {
    return (unsigned int)f2bf(a) | ((unsigned int)f2bf(b) << 16);
}

// ---------------------------------------------------------------------------
// basis_eval: 8 cubic B-spline values + silu. out[0..7]=basis, out[8]=silu.
// ---------------------------------------------------------------------------
__device__ __forceinline__ void basis_eval(
    float x, const float* __restrict__ grid, int ii, float out[9])
{
    float g[6];
#pragma unroll
    for (int k = 0; k < 6; ++k) g[k] = grid[(size_t)ii * 6 + k];
    float h = (g[5] - g[0]) * 0.2f;

    float t[12];
    t[0] = g[0] - 3.f * h; t[1] = g[0] - 2.f * h; t[2] = g[0] - h;
#pragma unroll
    for (int k = 0; k < 6; ++k) t[3 + k] = g[k];
    t[9] = g[5] + h; t[10] = g[5] + 2.f * h; t[11] = g[5] + 3.f * h;

    float Bv[11];
#pragma unroll
    for (int j = 0; j < 11; ++j)
        Bv[j] = (x >= t[j] && x < t[j + 1]) ? 1.0f : 0.0f;

#pragma unroll
    for (int d = 1; d <= 3; ++d) {
#pragma unroll
        for (int j = 0; j + d < 11; ++j) {
            float left  = __fdividef(x - t[j],         t[j + d] - t[j]);
            float right = __fdividef(t[j + d + 1] - x, t[j + d + 1] - t[j + 1]);
            Bv[j] = left * Bv[j] + right * Bv[j + 1];
        }
    }

#pragma unroll
    for (int k = 0; k < 8; ++k) out[k] = Bv[k];
    out[8] = __fdividef(x, 1.0f + __expf(-x));
}

// store 9 floats as one 32B bf16 record (16 slots, 9..15 zero)
__device__ __forceinline__ void store_rec16(unsigned short* rec, const float v[9])
{
    uint4* p = (uint4*)rec;
    p[0] = make_uint4(pack2(v[0], v[1]), pack2(v[2], v[3]),
                      pack2(v[4], v[5]), pack2(v[6], v[7]));
    p[1] = make_uint4(pack2(v[8], 0.f), 0u, 0u, 0u);
}

// ---------------------------------------------------------------------------
// merge: record s (= o*I+ii): [ssp*coef0..7, sb, 0..0] -> 32B record
// ---------------------------------------------------------------------------
__device__ __forceinline__ void merge_body(
    const float* __restrict__ coef, const float* __restrict__ ssp,
    const float* __restrict__ sb, unsigned short* __restrict__ wc16, int s)
{
    float sspv = ssp[s], sbv = sb[s];
    const float4* c = (const float4*)(coef + (size_t)s * 8);
    float4 c0 = c[0], c1 = c[1];
    float v[9] = { sspv * c0.x, sspv * c0.y, sspv * c0.z, sspv * c0.w,
                   sspv * c1.x, sspv * c1.y, sspv * c1.z, sspv * c1.w, sbv };
    store_rec16(wc16 + (size_t)s * 16, v);
}

// ---------------------------------------------------------------------------
// gemm0 fused v2 (128 blocks = 16 mt x 8 nt): one 32x32 tile (m=ii, n=b),
// 4 waves K-split (K2=4096 -> 32 steps, 2x2 frags, 128 MFMA/wave),
// LDS [4][32][33] reduce. Epilogue: xmid = D + bias0 -> basis_eval ->
// bas16_1 record (4 elements/thread).
// ---------------------------------------------------------------------------
__device__ __forceinline__ void gemm0_fused(
    const unsigned short* __restrict__ wc16_0, const unsigned short* __restrict__ bas16_0,
    const float* __restrict__ bias0, const float* __restrict__ grid1,
    unsigned short* __restrict__ bas16_1, int bid, float (*T)[32][33])
{
    constexpr int K2 = 256 * 16, KW = K2 / 4;
    int mt = bid >> 3, nt = bid & 7;
    int t = threadIdx.x, l = t & 63, w = t >> 6;
    int m0 = mt * 32;            // ii base (layer-1 input), [0,512)
    int n0 = nt * 32;            // b base, [0,256)

    f32x4 acc[2][2];
#pragma unroll
    for (int r = 0; r < 2; ++r)
#pragma unroll
        for (int c = 0; c < 2; ++c) acc[r][c] = {0.f, 0.f, 0.f, 0.f};

#pragma unroll 4
    for (int kk = 0; kk < KW / 32; ++kk) {   // 32 steps
        int koff = w * KW + kk * 32 + ((l >> 4) * 8);
        short8 a0 = *(const short8*)(wc16_0  + (size_t)(m0 +      (l & 15)) * K2 + koff);
        short8 a1 = *(const short8*)(wc16_0  + (size_t)(m0 + 16 + (l & 15)) * K2 + koff);
        short8 b0 = *(const short8*)(bas16_0 + (size_t)(n0 +      (l & 15)) * K2 + koff);
        short8 b1 = *(const short8*)(bas16_0 + (size_t)(n0 + 16 + (l & 15)) * K2 + koff);
        acc[0][0] = __builtin_amdgcn_mfma_f32_16x16x32_bf16(a0, b0, acc[0][0], 0, 0, 0);
        acc[0][1] = __builtin_amdgcn_mfma_f32_16x16x32_bf16(a0, b1, acc[0][1], 0, 0, 0);
        acc[1][0] = __builtin_amdgcn_mfma_f32_16x16x32_bf16(a1, b0, acc[1][0], 0, 0, 0);
        acc[1][1] = __builtin_amdgcn_mfma_f32_16x16x32_bf16(a1, b1, acc[1][1], 0, 0, 0);
    }

    // D layout (verified): col = l&15, row = (l>>4)*4 + reg
#pragma unroll
    for (int r16 = 0; r16 < 2; ++r16)
#pragma unroll
        for (int c16 = 0; c16 < 2; ++c16)
#pragma unroll
            for (int r = 0; r < 4; ++r)
                T[w][r16 * 16 + (l >> 4) * 4 + r][c16 * 16 + (l & 15)] = acc[r16][c16][r];
    __syncthreads();

#pragma unroll
    for (int e = t; e < 1024; e += 256) {
        int row = e >> 5, col = e & 31;       // row = ii_loc, col = b_loc
        float d = T[0][row][col] + T[1][row][col] + T[2][row][col] + T[3][row][col];
        int ii = m0 + row;
        float xv = d + bias0[ii];
        float out[9];
        basis_eval(xv, grid1, ii, out);
        store_rec16(bas16_1 + ((size_t)(n0 + col) * 512 + ii) * 16, out);
    }
    __syncthreads();
}

// ---------------------------------------------------------------------------
// gemm1 fused v2 (64 blocks = 8 mt x 8 nt): one 32x32 tile (m=b, n=o),
// 4 waves K-split (K2=8192 -> 64 steps, 2x2 frags), LDS reduce.
// Epilogue: x2[b][o] = D + bias1[o] (coalesced).
// ---------------------------------------------------------------------------
__device__ __forceinline__ void gemm1_fused(
    const unsigned short* __restrict__ bas16_1, const unsigned short* __restrict__ wc16_1,
    const float* __restrict__ bias1, float* __restrict__ x2, int bid, float (*T)[32][33])
{
    constexpr int K2 = 512 * 16, KW = K2 / 4;
    int mt = bid >> 3, nt = bid & 7;
    int t = threadIdx.x, l = t & 63, w = t >> 6;
    int m0 = mt * 32;            // b base
    int n0 = nt * 32;            // o base

    f32x4 acc[2][2];
#pragma unroll
    for (int r = 0; r < 2; ++r)
#pragma unroll
        for (int c = 0; c < 2; ++c) acc[r][c] = {0.f, 0.f, 0.f, 0.f};

#pragma unroll 4
    for (int kk = 0; kk < KW / 32; ++kk) {   // 64 steps
        int koff = w * KW + kk * 32 + ((l >> 4) * 8);
        short8 a0 = *(const short8*)(bas16_1 + (size_t)(m0 +      (l & 15)) * K2 + koff);
        short8 a1 = *(const short8*)(bas16_1 + (size_t)(m0 + 16 + (l & 15)) * K2 + koff);
        short8 b0 = *(const short8*)(wc16_1  + (size_t)(n0 +      (l & 15)) * K2 + koff);
        short8 b1 = *(const short8*)(wc16_1  + (size_t)(n0 + 16 + (l & 15)) * K2 + koff);
        acc[0][0] = __builtin_amdgcn_mfma_f32_16x16x32_bf16(a0, b0, acc[0][0], 0, 0, 0);
        acc[0][1] = __builtin_amdgcn_mfma_f32_16x16x32_bf16(a0, b1, acc[0][1], 0, 0, 0);
        acc[1][0] = __builtin_amdgcn_mfma_f32_16x16x32_bf16(a1, b0, acc[1][0], 0, 0, 0);
        acc[1][1] = __builtin_amdgcn_mfma_f32_16x16x32_bf16(a1, b1, acc[1][1], 0, 0, 0);
    }

#pragma unroll
    for (int r16 = 0; r16 < 2; ++r16)
#pragma unroll
        for (int c16 = 0; c16 < 2; ++c16)
#pragma unroll
            for (int r = 0; r < 4; ++r)
                T[w][r16 * 16 + (l >> 4) * 4 + r][c16 * 16 + (l & 15)] = acc[r16][c16][r];
    __syncthreads();

#pragma unroll
    for (int e = t; e < 1024; e += 256) {
        int row = e >> 5, col = e & 31;       // row = b_loc, col = o_loc
        float d = T[0][row][col] + T[1][row][col] + T[2][row][col] + T[3][row][col];
        int o = n0 + col;
        x2[(size_t)(m0 + row) * 256 + o] = d + bias1[o];
    }
}

// ---------------------------------------------------------------------------
// stats via 32x32x16 MFMA, 64 o's per wave (2 B-frags): task = (og, ii),
// og over O/64. Per b-tile (32 b's): 1 A-load + 2 MFMA + 96 VALU.
// D col=lane&31 (verified); row mapping cancels (summed over b).
// shfl_xor(32) -> full 256-b sums -> finalize sc/st inline. No atomics.
// ---------------------------------------------------------------------------
template <int I>
__device__ __forceinline__ void stats_mfma(
    const unsigned short* __restrict__ bas16, const unsigned short* __restrict__ wc16,
    const float* __restrict__ grid, float* __restrict__ sc, float* __restrict__ st,
    int id)   // id = og * I + ii
{
    int og = id / I, ii = id % I;
    int l = threadIdx.x & 63;
    int row = l & 31, chunk = l >> 5;

    short8 bf0 = *(const short8*)(
        wc16 + ((size_t)(og * 64 + row) * I + ii) * 16 + chunk * 8);
    short8 bf1 = *(const short8*)(
        wc16 + ((size_t)(og * 64 + 32 + row) * I + ii) * 16 + chunk * 8);

    float ab0 = 0.f, sm0 = 0.f, sq0 = 0.f;
    float ab1 = 0.f, sm1 = 0.f, sq1 = 0.f;
    for (int bt = 0; bt < BATCH / 32; ++bt) {   // 8 tiles
        short8 av = *(const short8*)(
            bas16 + ((size_t)(bt * 32 + row) * I + ii) * 16 + chunk * 8);
        f32x16 d0, d1;
#pragma unroll
        for (int r = 0; r < 16; ++r) { d0[r] = 0.f; d1[r] = 0.f; }
        d0 = __builtin_amdgcn_mfma_f32_32x32x16_bf16(av, bf0, d0, 0, 0, 0);
        d1 = __builtin_amdgcn_mfma_f32_32x32x16_bf16(av, bf1, d1, 0, 0, 0);
#pragma unroll
        for (int r = 0; r < 16; ++r) {
            float y0 = d0[r], y1 = d1[r];
            ab0 += fabsf(y0); sm0 += y0; sq0 = fmaf(y0, y0, sq0);
            ab1 += fabsf(y1); sm1 += y1; sq1 = fmaf(y1, y1, sq1);
        }
    }

    ab0 += __shfl_xor(ab0, 32); sm0 += __shfl_xor(sm0, 32); sq0 += __shfl_xor(sq0, 32);
    ab1 += __shfl_xor(ab1, 32); sm1 += __shfl_xor(sm1, 32); sq1 += __shfl_xor(sq1, 32);

    if (l < 32) {
#pragma unroll
        for (int half = 0; half < 2; ++half) {
            float ab = half ? ab1 : ab0;
            float sm = half ? sm1 : sm0;
            float sq = half ? sq1 : sq0;
            int o = og * 64 + half * 32 + l;
            size_t s = (size_t)o * I + ii;
            float range = grid[s * 6 + 5] - grid[s * 6] + 1e-4f;
            sc[s] = (ab * (1.0f / BATCH)) / range;
            float var = (sq - sm * sm * (1.0f / BATCH)) * (1.0f / (BATCH - 1));
            st[s] = sqrtf(fmaxf(var, 0.0f));
        }
    }
}

// ---------------------------------------------------------------------------
// K1: merge0(512) | basis0(256, ii-lane-fast)                -> 768 blocks
// ---------------------------------------------------------------------------
__global__ __launch_bounds__(256) void k1_prep(
    const float* __restrict__ coef0, const float* __restrict__ ssp0,
    const float* __restrict__ sb0,   unsigned short* __restrict__ wc16_0,
    const float* __restrict__ x, const float* __restrict__ grid0,
    unsigned short* __restrict__ bas16_0)
{
    int bid = blockIdx.x, t = threadIdx.x;
    if (bid < 512) { merge_body(coef0, ssp0, sb0, wc16_0, bid * 256 + t); return; }
    int tile = bid - 512;                  // 16 bt x 16 it
    int bt = tile >> 4, it = tile & 15;
    int ii = it * 16 + (t & 15), b = bt * 16 + (t >> 4);
    float out[9];
    basis_eval(x[(size_t)b * 256 + ii], grid0, ii, out);
    store_rec16(bas16_0 + ((size_t)b * 256 + ii) * 16, out);
}

// ---------------------------------------------------------------------------
// K2: gemm0-fused(128) | stats0-mfma(512) | merge1(512)      -> 1152 blocks
// ---------------------------------------------------------------------------
__global__ __launch_bounds__(256) void k2_sweep0(
    const unsigned short* __restrict__ wc16_0, const unsigned short* __restrict__ bas16_0,
    const float* __restrict__ bias0, const float* __restrict__ grid1,
    unsigned short* __restrict__ bas16_1,
    const float* __restrict__ grid0, float* __restrict__ sc0, float* __restrict__ st0,
    const float* __restrict__ coef1, const float* __restrict__ ssp1,
    const float* __restrict__ sb1,   unsigned short* __restrict__ wc16_1)
{
    __shared__ float Tsh[4][32][33];
    int bid = blockIdx.x;
    if (bid < 128) {
        gemm0_fused(wc16_0, bas16_0, bias0, grid1, bas16_1, bid, Tsh);
    } else if (bid < 640) {
        // 2048 tasks: og in [0,8), ii in [0,256)
        int id = (bid - 128) * 4 + (threadIdx.x >> 6);
        stats_mfma<256>(bas16_0, wc16_0, grid0, sc0, st0, id);
    } else {
        merge_body(coef1, ssp1, sb1, wc16_1, (bid - 640) * 256 + threadIdx.x);
    }
}

// ---------------------------------------------------------------------------
// K3: gemm1-fused(64) | stats1-mfma(512)                     -> 576 blocks
// ---------------------------------------------------------------------------
__global__ __launch_bounds__(256) void k3_sweep1(
    const unsigned short* __restrict__ bas16_1, const unsigned short* __restrict__ wc16_1,
    const float* __restrict__ bias1, float* __restrict__ x2,
    const float* __restrict__ grid1, float* __restrict__ sc1, float* __restrict__ st1)
{
    __shared__ float Tsh[4][32][33];
    int bid = blockIdx.x;
    if (bid < 64) {
        gemm1_fused(bas16_1, wc16_1, bias1, x2, bid, Tsh);
    } else {
        // 2048 tasks: og in [0,4), ii in [0,512)
        int id = (bid - 64) * 4 + (threadIdx.x >> 6);
        stats_mfma<512>(bas16_1, wc16_1, grid1, sc1, st1, id);
    }
}

// ---------------------------------------------------------------------------
extern "C" void kernel_launch(void* const* d_in, const int* in_sizes, int n_in,
                              void* d_out, int out_size, void* d_ws, size_t ws_size,
                              hipStream_t stream)
{
    const float* x     = (const float*)d_in[0];
    const float* grid0 = (const float*)d_in[1];
    const float* coef0 = (const float*)d_in[2];
    const float* sb0   = (const float*)d_in[3];
    const float* ssp0  = (const float*)d_in[4];
    const float* bias0 = (const float*)d_in[5];
    const float* grid1 = (const float*)d_in[6];
    const float* coef1 = (const float*)d_in[7];
    const float* sb1   = (const float*)d_in[8];
    const float* ssp1  = (const float*)d_in[9];
    const float* bias1 = (const float*)d_in[10];

    float* out = (float*)d_out;
    float* x2  = out;                 // (256,256)
    float* sc0 = out + 65536;         // (512,256)
    float* st0 = out + 196608;        // (512,256)
    float* sc1 = out + 327680;        // (256,512)
    float* st1 = out + 458752;        // (256,512)

    // Workspace (~14 MB, all disjoint): one 32B record per element.
    char* w = (char*)d_ws;
    unsigned short* wc16_0  = (unsigned short*)w; w += (size_t)131072 * 32;
    unsigned short* wc16_1  = (unsigned short*)w; w += (size_t)131072 * 32;
    unsigned short* bas16_0 = (unsigned short*)w; w += (size_t)65536 * 32;
    unsigned short* bas16_1 = (unsigned short*)w; w += (size_t)131072 * 32;

    k1_prep<<<768, 256, 0, stream>>>(
        coef0, ssp0, sb0, wc16_0, x, grid0, bas16_0);

    k2_sweep0<<<1152, 256, 0, stream>>>(
        wc16_0, bas16_0, bias0, grid1, bas16_1,
        grid0, sc0, st0, coef1, ssp1, sb1, wc16_1);

    k3_sweep1<<<576, 256, 0, stream>>>(
        bas16_1, wc16_1, bias1, x2, grid1, sc1, st1);
}

// Round 20
// 56.138 us; speedup vs baseline: 1.3701x; 1.3701x over previous
//
#include <hip/hip_runtime.h>
#include <math.h>

constexpr int BATCH = 256;

typedef short short8 __attribute__((ext_vector_type(8)));
typedef float f32x4 __attribute__((ext_vector_type(4)));
typedef float f32x16 __attribute__((ext_vector_type(16)));

// ---------------------------------------------------------------------------
// bf16 helpers (RNE)
// ---------------------------------------------------------------------------
__device__ __forceinline__ unsigned short f2bf(float f) {
    unsigned int u = __float_as_uint(f);
    u += 0x7FFFu + ((u >> 16) & 1u);
    return (unsigned short)(u >> 16);
}
__device__ __forceinline__ unsigned int pack2(float a, float b) {
    return (unsigned int)f2bf(a) | ((unsigned int)f2bf(b) << 16);
}

// ---------------------------------------------------------------------------
// basis_eval: 8 cubic B-spline values + silu. out[0..7]=basis, out[8]=silu.
// ---------------------------------------------------------------------------
__device__ __forceinline__ void basis_eval(
    float x, const float* __restrict__ grid, int ii, float out[9])
{
    float g[6];
#pragma unroll
    for (int k = 0; k < 6; ++k) g[k] = grid[(size_t)ii * 6 + k];
    float h = (g[5] - g[0]) * 0.2f;

    float t[12];
    t[0] = g[0] - 3.f * h; t[1] = g[0] - 2.f * h; t[2] = g[0] - h;
#pragma unroll
    for (int k = 0; k < 6; ++k) t[3 + k] = g[k];
    t[9] = g[5] + h; t[10] = g[5] + 2.f * h; t[11] = g[5] + 3.f * h;

    float Bv[11];
#pragma unroll
    for (int j = 0; j < 11; ++j)
        Bv[j] = (x >= t[j] && x < t[j + 1]) ? 1.0f : 0.0f;

#pragma unroll
    for (int d = 1; d <= 3; ++d) {
#pragma unroll
        for (int j = 0; j + d < 11; ++j) {
            float left  = __fdividef(x - t[j],         t[j + d] - t[j]);
            float right = __fdividef(t[j + d + 1] - x, t[j + d + 1] - t[j + 1]);
            Bv[j] = left * Bv[j] + right * Bv[j + 1];
        }
    }

#pragma unroll
    for (int k = 0; k < 8; ++k) out[k] = Bv[k];
    out[8] = __fdividef(x, 1.0f + __expf(-x));
}

// store 9 floats as one 32B bf16 record (16 slots, 9..15 zero)
__device__ __forceinline__ void store_rec16(unsigned short* rec, const float v[9])
{
    uint4* p = (uint4*)rec;
    p[0] = make_uint4(pack2(v[0], v[1]), pack2(v[2], v[3]),
                      pack2(v[4], v[5]), pack2(v[6], v[7]));
    p[1] = make_uint4(pack2(v[8], 0.f), 0u, 0u, 0u);
}

// ---------------------------------------------------------------------------
// merge: record s (= o*I+ii): [ssp*coef0..7, sb, 0..0] -> 32B record
// ---------------------------------------------------------------------------
__device__ __forceinline__ void merge_body(
    const float* __restrict__ coef, const float* __restrict__ ssp,
    const float* __restrict__ sb, unsigned short* __restrict__ wc16, int s)
{
    float sspv = ssp[s], sbv = sb[s];
    const float4* c = (const float4*)(coef + (size_t)s * 8);
    float4 c0 = c[0], c1 = c[1];
    float v[9] = { sspv * c0.x, sspv * c0.y, sspv * c0.z, sspv * c0.w,
                   sspv * c1.x, sspv * c1.y, sspv * c1.z, sspv * c1.w, sbv };
    store_rec16(wc16 + (size_t)s * 16, v);
}

// ---------------------------------------------------------------------------
// gemm0 fused (512 tasks = 32 mt x 16 nt): one 16x16 tile (m=ii, n=b),
// 4 waves split K (K2=4096 -> 32-MFMA chain each), LDS reduce.
// Epilogue: xmid = D + bias0 -> basis_eval -> bas16_1 record.
// ---------------------------------------------------------------------------
__device__ __forceinline__ void gemm0_fused(
    const unsigned short* __restrict__ wc16_0, const unsigned short* __restrict__ bas16_0,
    const float* __restrict__ bias0, const float* __restrict__ grid1,
    unsigned short* __restrict__ bas16_1, int bid, float (*T)[16][17])
{
    constexpr int K2 = 256 * 16, KW = K2 / 4;
    int mt = bid >> 4, nt = bid & 15;
    int t = threadIdx.x, l = t & 63, w = t >> 6;
    int m0 = mt * 16;            // ii base (layer-1 input)
    int n0 = nt * 16;            // b base

    const unsigned short* pa = wc16_0  + (size_t)(m0 + (l & 15)) * K2 + w * KW + ((l >> 4) * 8);
    const unsigned short* pb = bas16_0 + (size_t)(n0 + (l & 15)) * K2 + w * KW + ((l >> 4) * 8);

    f32x4 acc = {0.f, 0.f, 0.f, 0.f};
#pragma unroll 8
    for (int kk = 0; kk < KW / 32; ++kk) {   // 32 steps
        short8 av = *(const short8*)pa; pa += 32;
        short8 bv = *(const short8*)pb; pb += 32;
        acc = __builtin_amdgcn_mfma_f32_16x16x32_bf16(av, bv, acc, 0, 0, 0);
    }

#pragma unroll
    for (int r = 0; r < 4; ++r)
        T[w][(l >> 4) * 4 + r][l & 15] = acc[r];   // [m_loc][n_loc]
    __syncthreads();

    int ii_loc = t & 15, b_loc = t >> 4;     // thread owns one element
    float d = T[0][ii_loc][b_loc] + T[1][ii_loc][b_loc]
            + T[2][ii_loc][b_loc] + T[3][ii_loc][b_loc];
    int ii = m0 + ii_loc;
    float xv = d + bias0[ii];
    float out[9];
    basis_eval(xv, grid1, ii, out);
    store_rec16(bas16_1 + ((size_t)(n0 + b_loc) * 512 + ii) * 16, out);
    __syncthreads();
}

// ---------------------------------------------------------------------------
// gemm1 fused (256 tasks = 16 mt x 16 nt): one 16x16 tile (m=b, n=o),
// 4 waves split K (K2=8192 -> 64-MFMA chain each), LDS reduce.
// Epilogue: x2[b][o] = D + bias1[o].
// ---------------------------------------------------------------------------
__device__ __forceinline__ void gemm1_fused(
    const unsigned short* __restrict__ bas16_1, const unsigned short* __restrict__ wc16_1,
    const float* __restrict__ bias1, float* __restrict__ x2, int bid, float (*T)[16][17])
{
    constexpr int K2 = 512 * 16, KW = K2 / 4;
    int mt = bid >> 4, nt = bid & 15;
    int t = threadIdx.x, l = t & 63, w = t >> 6;
    int m0 = mt * 16;            // b base
    int n0 = nt * 16;            // o base

    const unsigned short* pa = bas16_1 + (size_t)(m0 + (l & 15)) * K2 + w * KW + ((l >> 4) * 8);
    const unsigned short* pb = wc16_1  + (size_t)(n0 + (l & 15)) * K2 + w * KW + ((l >> 4) * 8);

    f32x4 acc = {0.f, 0.f, 0.f, 0.f};
#pragma unroll 8
    for (int kk = 0; kk < KW / 32; ++kk) {   // 64 steps
        short8 av = *(const short8*)pa; pa += 32;
        short8 bv = *(const short8*)pb; pb += 32;
        acc = __builtin_amdgcn_mfma_f32_16x16x32_bf16(av, bv, acc, 0, 0, 0);
    }

#pragma unroll
    for (int r = 0; r < 4; ++r)
        T[w][(l >> 4) * 4 + r][l & 15] = acc[r];   // [b_loc][o_loc]
    __syncthreads();

    int o_loc = t & 15, b_loc = t >> 4;
    float d = T[0][b_loc][o_loc] + T[1][b_loc][o_loc]
            + T[2][b_loc][o_loc] + T[3][b_loc][o_loc];
    int o = n0 + o_loc;
    x2[(size_t)(m0 + b_loc) * 256 + o] = d + bias1[o];
}

// ---------------------------------------------------------------------------
// stats via 32x32x16 MFMA: one wave-task = (og, ii) covering 32 o's x 256 b.
// A = bas16 (row=b), B = wc16 (row=o), D[row=b][col=o] = y (K=16, 9 valid).
// D col=lane&31 (verified); row mapping cancels (summed over b).
// shfl_xor(32) -> full b-sum -> finalize sc/st inline. No atomics.
// ---------------------------------------------------------------------------
template <int I>
__device__ __forceinline__ void stats_mfma(
    const unsigned short* __restrict__ bas16, const unsigned short* __restrict__ wc16,
    const float* __restrict__ grid, float* __restrict__ sc, float* __restrict__ st,
    int id)   // id = og * I + ii
{
    int og = id / I, ii = id % I;
    int l = threadIdx.x & 63;
    int row = l & 31, chunk = l >> 5;

    short8 bfrag = *(const short8*)(
        wc16 + ((size_t)(og * 32 + row) * I + ii) * 16 + chunk * 8);

    float ab = 0.f, sm = 0.f, sq = 0.f;
    for (int bt = 0; bt < BATCH / 32; ++bt) {   // 8 tiles
        int b = bt * 32 + row;
        short8 av = *(const short8*)(
            bas16 + ((size_t)b * I + ii) * 16 + chunk * 8);
        f32x16 d;
#pragma unroll
        for (int r = 0; r < 16; ++r) d[r] = 0.f;
        d = __builtin_amdgcn_mfma_f32_32x32x16_bf16(av, bfrag, d, 0, 0, 0);
#pragma unroll
        for (int r = 0; r < 16; ++r) {
            float y = d[r];
            ab += fabsf(y);
            sm += y;
            sq = fmaf(y, y, sq);
        }
    }

    ab += __shfl_xor(ab, 32);
    sm += __shfl_xor(sm, 32);
    sq += __shfl_xor(sq, 32);

    if (l < 32) {
        int o = og * 32 + l;
        size_t s = (size_t)o * I + ii;
        float range = grid[s * 6 + 5] - grid[s * 6] + 1e-4f;
        sc[s] = (ab * (1.0f / BATCH)) / range;
        float var = (sq - sm * sm * (1.0f / BATCH)) * (1.0f / (BATCH - 1));
        st[s] = sqrtf(fmaxf(var, 0.0f));
    }
}

// ---------------------------------------------------------------------------
// K1: merge0(512) | basis0(256, ii-lane-fast)                -> 768 blocks
// ---------------------------------------------------------------------------
__global__ __launch_bounds__(256) void k1_prep(
    const float* __restrict__ coef0, const float* __restrict__ ssp0,
    const float* __restrict__ sb0,   unsigned short* __restrict__ wc16_0,
    const float* __restrict__ x, const float* __restrict__ grid0,
    unsigned short* __restrict__ bas16_0)
{
    int bid = blockIdx.x, t = threadIdx.x;
    if (bid < 512) { merge_body(coef0, ssp0, sb0, wc16_0, bid * 256 + t); return; }
    int tile = bid - 512;                  // 16 bt x 16 it
    int bt = tile >> 4, it = tile & 15;
    int ii = it * 16 + (t & 15), b = bt * 16 + (t >> 4);
    float out[9];
    basis_eval(x[(size_t)b * 256 + ii], grid0, ii, out);
    store_rec16(bas16_0 + ((size_t)b * 256 + ii) * 16, out);
}

// ---------------------------------------------------------------------------
// K2: gemm0-fused(512) | stats0-mfma(1024) | merge1(512)     -> 2048 blocks
// ---------------------------------------------------------------------------
__global__ __launch_bounds__(256) void k2_sweep0(
    const unsigned short* __restrict__ wc16_0, const unsigned short* __restrict__ bas16_0,
    const float* __restrict__ bias0, const float* __restrict__ grid1,
    unsigned short* __restrict__ bas16_1,
    const float* __restrict__ grid0, float* __restrict__ sc0, float* __restrict__ st0,
    const float* __restrict__ coef1, const float* __restrict__ ssp1,
    const float* __restrict__ sb1,   unsigned short* __restrict__ wc16_1)
{
    __shared__ float Tsh[4][16][17];
    int bid = blockIdx.x;
    if (bid < 512) {
        gemm0_fused(wc16_0, bas16_0, bias0, grid1, bas16_1, bid, Tsh);
    } else if (bid < 1536) {
        // 4096 tasks: og in [0,16), ii in [0,256)
        int id = (bid - 512) * 4 + (threadIdx.x >> 6);
        stats_mfma<256>(bas16_0, wc16_0, grid0, sc0, st0, id);
    } else {
        merge_body(coef1, ssp1, sb1, wc16_1, (bid - 1536) * 256 + threadIdx.x);
    }
}

// ---------------------------------------------------------------------------
// K3: gemm1-fused(256) | stats1-mfma(1024) -> 1280 blocks
// ---------------------------------------------------------------------------
__global__ __launch_bounds__(256) void k3_sweep1(
    const unsigned short* __restrict__ bas16_1, const unsigned short* __restrict__ wc16_1,
    const float* __restrict__ bias1, float* __restrict__ x2,
    const float* __restrict__ grid1, float* __restrict__ sc1, float* __restrict__ st1)
{
    __shared__ float Tsh[4][16][17];
    int bid = blockIdx.x;
    if (bid < 256) {
        gemm1_fused(bas16_1, wc16_1, bias1, x2, bid, Tsh);
    } else {
        // 4096 tasks: og in [0,8), ii in [0,512)
        int id = (bid - 256) * 4 + (threadIdx.x >> 6);
        stats_mfma<512>(bas16_1, wc16_1, grid1, sc1, st1, id);
    }
}

// ---------------------------------------------------------------------------
extern "C" void kernel_launch(void* const* d_in, const int* in_sizes, int n_in,
                              void* d_out, int out_size, void* d_ws, size_t ws_size,
                              hipStream_t stream)
{
    const float* x     = (const float*)d_in[0];
    const float* grid0 = (const float*)d_in[1];
    const float* coef0 = (const float*)d_in[2];
    const float* sb0   = (const float*)d_in[3];
    const float* ssp0  = (const float*)d_in[4];
    const float* bias0 = (const float*)d_in[5];
    const float* grid1 = (const float*)d_in[6];
    const float* coef1 = (const float*)d_in[7];
    const float* sb1   = (const float*)d_in[8];
    const float* ssp1  = (const float*)d_in[9];
    const float* bias1 = (const float*)d_in[10];

    float* out = (float*)d_out;
    float* x2  = out;                 // (256,256)
    float* sc0 = out + 65536;         // (512,256)
    float* st0 = out + 196608;        // (512,256)
    float* sc1 = out + 327680;        // (256,512)
    float* st1 = out + 458752;        // (256,512)

    // Workspace (~14 MB, all disjoint): one 32B record per element.
    char* w = (char*)d_ws;
    unsigned short* wc16_0  = (unsigned short*)w; w += (size_t)131072 * 32;
    unsigned short* wc16_1  = (unsigned short*)w; w += (size_t)131072 * 32;
    unsigned short* bas16_0 = (unsigned short*)w; w += (size_t)65536 * 32;
    unsigned short* bas16_1 = (unsigned short*)w; w += (size_t)131072 * 32;

    k1_prep<<<768, 256, 0, stream>>>(
        coef0, ssp0, sb0, wc16_0, x, grid0, bas16_0);

    k2_sweep0<<<2048, 256, 0, stream>>>(
        wc16_0, bas16_0, bias0, grid1, bas16_1,
        grid0, sc0, st0, coef1, ssp1, sb1, wc16_1);

    k3_sweep1<<<1280, 256, 0, stream>>>(
        bas16_1, wc16_1, bias1, x2, grid1, sc1, st1);
}

// Round 21
// 56.076 us; speedup vs baseline: 1.3716x; 1.0011x over previous
//
#include <hip/hip_runtime.h>
#include <math.h>

constexpr int BATCH = 256;

typedef short short8 __attribute__((ext_vector_type(8)));
typedef float f32x4 __attribute__((ext_vector_type(4)));
typedef float f32x16 __attribute__((ext_vector_type(16)));

// ---------------------------------------------------------------------------
// bf16 helpers (RNE)
// ---------------------------------------------------------------------------
__device__ __forceinline__ unsigned short f2bf(float f) {
    unsigned int u = __float_as_uint(f);
    u += 0x7FFFu + ((u >> 16) & 1u);
    return (unsigned short)(u >> 16);
}
__device__ __forceinline__ unsigned int pack2(float a, float b) {
    return (unsigned int)f2bf(a) | ((unsigned int)f2bf(b) << 16);
}

// ---------------------------------------------------------------------------
// basis_eval: 8 cubic B-spline values + silu. out[0..7]=basis, out[8]=silu.
// ---------------------------------------------------------------------------
__device__ __forceinline__ void basis_eval(
    float x, const float* __restrict__ grid, int ii, float out[9])
{
    float g[6];
#pragma unroll
    for (int k = 0; k < 6; ++k) g[k] = grid[(size_t)ii * 6 + k];
    float h = (g[5] - g[0]) * 0.2f;

    float t[12];
    t[0] = g[0] - 3.f * h; t[1] = g[0] - 2.f * h; t[2] = g[0] - h;
#pragma unroll
    for (int k = 0; k < 6; ++k) t[3 + k] = g[k];
    t[9] = g[5] + h; t[10] = g[5] + 2.f * h; t[11] = g[5] + 3.f * h;

    float Bv[11];
#pragma unroll
    for (int j = 0; j < 11; ++j)
        Bv[j] = (x >= t[j] && x < t[j + 1]) ? 1.0f : 0.0f;

#pragma unroll
    for (int d = 1; d <= 3; ++d) {
#pragma unroll
        for (int j = 0; j + d < 11; ++j) {
            float left  = __fdividef(x - t[j],         t[j + d] - t[j]);
            float right = __fdividef(t[j + d + 1] - x, t[j + d + 1] - t[j + 1]);
            Bv[j] = left * Bv[j] + right * Bv[j + 1];
        }
    }

#pragma unroll
    for (int k = 0; k < 8; ++k) out[k] = Bv[k];
    out[8] = __fdividef(x, 1.0f + __expf(-x));
}

// store 9 floats as one 32B bf16 record (16 slots, 9..15 zero)
__device__ __forceinline__ void store_rec16(unsigned short* rec, const float v[9])
{
    uint4* p = (uint4*)rec;
    p[0] = make_uint4(pack2(v[0], v[1]), pack2(v[2], v[3]),
                      pack2(v[4], v[5]), pack2(v[6], v[7]));
    p[1] = make_uint4(pack2(v[8], 0.f), 0u, 0u, 0u);
}

// ---------------------------------------------------------------------------
// merge: record s (= o*I+ii): [ssp*coef0..7, sb, 0..0] -> 32B record
// ---------------------------------------------------------------------------
__device__ __forceinline__ void merge_body(
    const float* __restrict__ coef, const float* __restrict__ ssp,
    const float* __restrict__ sb, unsigned short* __restrict__ wc16, int s)
{
    float sspv = ssp[s], sbv = sb[s];
    const float4* c = (const float4*)(coef + (size_t)s * 8);
    float4 c0 = c[0], c1 = c[1];
    float v[9] = { sspv * c0.x, sspv * c0.y, sspv * c0.z, sspv * c0.w,
                   sspv * c1.x, sspv * c1.y, sspv * c1.z, sspv * c1.w, sbv };
    store_rec16(wc16 + (size_t)s * 16, v);
}

// ---------------------------------------------------------------------------
// gemm0 fused (512 tasks): one 16x16 tile (m=ii, n=b), 4 waves K-split
// (K2=4096 -> 32-MFMA chain each), LDS reduce.
// XCD swizzle: xcd=bid&7 owns mt-panel of 4 -> per-XCD working set 2.5 MB.
// Epilogue: xmid = D + bias0 -> basis_eval -> bas16_1 record.
// ---------------------------------------------------------------------------
__device__ __forceinline__ void gemm0_fused(
    const unsigned short* __restrict__ wc16_0, const unsigned short* __restrict__ bas16_0,
    const float* __restrict__ bias0, const float* __restrict__ grid1,
    unsigned short* __restrict__ bas16_1, int bid, float (*T)[16][17])
{
    constexpr int K2 = 256 * 16, KW = K2 / 4;
    int xcd = bid & 7, j = bid >> 3;        // j in [0,64)
    int mt = xcd * 4 + (j & 3);             // [0,32)
    int nt = j >> 2;                        // [0,16)
    int t = threadIdx.x, l = t & 63, w = t >> 6;
    int m0 = mt * 16;            // ii base (layer-1 input)
    int n0 = nt * 16;            // b base

    const unsigned short* pa = wc16_0  + (size_t)(m0 + (l & 15)) * K2 + w * KW + ((l >> 4) * 8);
    const unsigned short* pb = bas16_0 + (size_t)(n0 + (l & 15)) * K2 + w * KW + ((l >> 4) * 8);

    f32x4 acc = {0.f, 0.f, 0.f, 0.f};
#pragma unroll 8
    for (int kk = 0; kk < KW / 32; ++kk) {   // 32 steps
        short8 av = *(const short8*)pa; pa += 32;
        short8 bv = *(const short8*)pb; pb += 32;
        acc = __builtin_amdgcn_mfma_f32_16x16x32_bf16(av, bv, acc, 0, 0, 0);
    }

#pragma unroll
    for (int r = 0; r < 4; ++r)
        T[w][(l >> 4) * 4 + r][l & 15] = acc[r];   // [m_loc][n_loc]
    __syncthreads();

    int ii_loc = t & 15, b_loc = t >> 4;     // thread owns one element
    float d = T[0][ii_loc][b_loc] + T[1][ii_loc][b_loc]
            + T[2][ii_loc][b_loc] + T[3][ii_loc][b_loc];
    int ii = m0 + ii_loc;
    float xv = d + bias0[ii];
    float out[9];
    basis_eval(xv, grid1, ii, out);
    store_rec16(bas16_1 + ((size_t)(n0 + b_loc) * 512 + ii) * 16, out);
    __syncthreads();
}

// ---------------------------------------------------------------------------
// gemm1 fused (256 tasks): one 16x16 tile (m=b, n=o), 4 waves K-split
// (K2=8192 -> 64-MFMA chain each), LDS reduce.
// XCD swizzle: xcd=(mtg,ntg) 4x2 quadrants -> per-XCD working set 3 MB.
// Epilogue: x2[b][o] = D + bias1[o].
// ---------------------------------------------------------------------------
__device__ __forceinline__ void gemm1_fused(
    const unsigned short* __restrict__ bas16_1, const unsigned short* __restrict__ wc16_1,
    const float* __restrict__ bias1, float* __restrict__ x2, int bid, float (*T)[16][17])
{
    constexpr int K2 = 512 * 16, KW = K2 / 4;
    int xcd = bid & 7, j = bid >> 3;        // j in [0,32)
    int mt = (xcd >> 1) * 4 + (j & 3);      // [0,16)
    int nt = (xcd & 1) * 8 + (j >> 2);      // [0,16)
    int t = threadIdx.x, l = t & 63, w = t >> 6;
    int m0 = mt * 16;            // b base
    int n0 = nt * 16;            // o base

    const unsigned short* pa = bas16_1 + (size_t)(m0 + (l & 15)) * K2 + w * KW + ((l >> 4) * 8);
    const unsigned short* pb = wc16_1  + (size_t)(n0 + (l & 15)) * K2 + w * KW + ((l >> 4) * 8);

    f32x4 acc = {0.f, 0.f, 0.f, 0.f};
#pragma unroll 8
    for (int kk = 0; kk < KW / 32; ++kk) {   // 64 steps
        short8 av = *(const short8*)pa; pa += 32;
        short8 bv = *(const short8*)pb; pb += 32;
        acc = __builtin_amdgcn_mfma_f32_16x16x32_bf16(av, bv, acc, 0, 0, 0);
    }

#pragma unroll
    for (int r = 0; r < 4; ++r)
        T[w][(l >> 4) * 4 + r][l & 15] = acc[r];   // [b_loc][o_loc]
    __syncthreads();

    int o_loc = t & 15, b_loc = t >> 4;
    float d = T[0][b_loc][o_loc] + T[1][b_loc][o_loc]
            + T[2][b_loc][o_loc] + T[3][b_loc][o_loc];
    int o = n0 + o_loc;
    x2[(size_t)(m0 + b_loc) * 256 + o] = d + bias1[o];
}

// ---------------------------------------------------------------------------
// stats via 32x32x16 MFMA: one wave-task = (og, ii) covering 32 o's x 256 b.
// A = bas16 (row=b), B = wc16 (row=o), D[row=b][col=o] = y (K=16, 9 valid).
// D col=lane&31 (verified); row mapping cancels (summed over b).
// shfl_xor(32) -> full b-sum -> finalize sc/st inline. No atomics.
// ---------------------------------------------------------------------------
template <int I>
__device__ __forceinline__ void stats_mfma(
    const unsigned short* __restrict__ bas16, const unsigned short* __restrict__ wc16,
    const float* __restrict__ grid, float* __restrict__ sc, float* __restrict__ st,
    int og, int ii)
{
    int l = threadIdx.x & 63;
    int row = l & 31, chunk = l >> 5;

    short8 bfrag = *(const short8*)(
        wc16 + ((size_t)(og * 32 + row) * I + ii) * 16 + chunk * 8);

    float ab = 0.f, sm = 0.f, sq = 0.f;
    for (int bt = 0; bt < BATCH / 32; ++bt) {   // 8 tiles
        int b = bt * 32 + row;
        short8 av = *(const short8*)(
            bas16 + ((size_t)b * I + ii) * 16 + chunk * 8);
        f32x16 d;
#pragma unroll
        for (int r = 0; r < 16; ++r) d[r] = 0.f;
        d = __builtin_amdgcn_mfma_f32_32x32x16_bf16(av, bfrag, d, 0, 0, 0);
#pragma unroll
        for (int r = 0; r < 16; ++r) {
            float y = d[r];
            ab += fabsf(y);
            sm += y;
            sq = fmaf(y, y, sq);
        }
    }

    ab += __shfl_xor(ab, 32);
    sm += __shfl_xor(sm, 32);
    sq += __shfl_xor(sq, 32);

    if (l < 32) {
        int o = og * 32 + l;
        size_t s = (size_t)o * I + ii;
        float range = grid[s * 6 + 5] - grid[s * 6] + 1e-4f;
        sc[s] = (ab * (1.0f / BATCH)) / range;
        float var = (sq - sm * sm * (1.0f / BATCH)) * (1.0f / (BATCH - 1));
        st[s] = sqrtf(fmaxf(var, 0.0f));
    }
}

// ---------------------------------------------------------------------------
// K1: merge0(512) | basis0(256, ii-lane-fast)                -> 768 blocks
// ---------------------------------------------------------------------------
__global__ __launch_bounds__(256) void k1_prep(
    const float* __restrict__ coef0, const float* __restrict__ ssp0,
    const float* __restrict__ sb0,   unsigned short* __restrict__ wc16_0,
    const float* __restrict__ x, const float* __restrict__ grid0,
    unsigned short* __restrict__ bas16_0)
{
    int bid = blockIdx.x, t = threadIdx.x;
    if (bid < 512) { merge_body(coef0, ssp0, sb0, wc16_0, bid * 256 + t); return; }
    int tile = bid - 512;                  // 16 bt x 16 it
    int bt = tile >> 4, it = tile & 15;
    int ii = it * 16 + (t & 15), b = bt * 16 + (t >> 4);
    float out[9];
    basis_eval(x[(size_t)b * 256 + ii], grid0, ii, out);
    store_rec16(bas16_0 + ((size_t)b * 256 + ii) * 16, out);
}

// ---------------------------------------------------------------------------
// K2: gemm0-fused(512) | stats0-mfma(1024) | merge1(512)     -> 2048 blocks
// stats0 XCD swizzle: xcd owns 2 og's (wc slice 512KB + bas 2MB = 2.5MB/L2).
// ---------------------------------------------------------------------------
__global__ __launch_bounds__(256) void k2_sweep0(
    const unsigned short* __restrict__ wc16_0, const unsigned short* __restrict__ bas16_0,
    const float* __restrict__ bias0, const float* __restrict__ grid1,
    unsigned short* __restrict__ bas16_1,
    const float* __restrict__ grid0, float* __restrict__ sc0, float* __restrict__ st0,
    const float* __restrict__ coef1, const float* __restrict__ ssp1,
    const float* __restrict__ sb1,   unsigned short* __restrict__ wc16_1)
{
    __shared__ float Tsh[4][16][17];
    int bid = blockIdx.x;
    if (bid < 512) {
        gemm0_fused(wc16_0, bas16_0, bias0, grid1, bas16_1, bid, Tsh);
    } else if (bid < 1536) {
        // 4096 tasks: og in [0,16), ii in [0,256). blockrel 512-aligned -> xcd = rel&7.
        int rel = bid - 512;                 // [0,1024)
        int xcd = rel & 7, j = rel >> 3;     // j in [0,128)
        int og = xcd * 2 + (j & 1);          // [0,16)
        int ii = (j >> 1) * 4 + (threadIdx.x >> 6);   // [0,256)
        stats_mfma<256>(bas16_0, wc16_0, grid0, sc0, st0, og, ii);
    } else {
        merge_body(coef1, ssp1, sb1, wc16_1, (bid - 1536) * 256 + threadIdx.x);
    }
}

// ---------------------------------------------------------------------------
// K3: gemm1-fused(256) | stats1-mfma(1024)                   -> 1280 blocks
// stats1 XCD swizzle: xcd = (og-pair, ii-half) -> 3MB per-XCD working set.
// ---------------------------------------------------------------------------
__global__ __launch_bounds__(256) void k3_sweep1(
    const unsigned short* __restrict__ bas16_1, const unsigned short* __restrict__ wc16_1,
    const float* __restrict__ bias1, float* __restrict__ x2,
    const float* __restrict__ grid1, float* __restrict__ sc1, float* __restrict__ st1)
{
    __shared__ float Tsh[4][16][17];
    int bid = blockIdx.x;
    if (bid < 256) {
        gemm1_fused(bas16_1, wc16_1, bias1, x2, bid, Tsh);
    } else {
        // 4096 tasks: og in [0,8), ii in [0,512). blockrel 256-aligned -> xcd = rel&7.
        int rel = bid - 256;                 // [0,1024)
        int xcd = rel & 7, j = rel >> 3;     // j in [0,128)
        int og = (xcd >> 1) * 2 + (j & 1);   // [0,8)
        int ii_blk = (xcd & 1) * 64 + (j >> 1);       // [0,128)
        int ii = ii_blk * 4 + (threadIdx.x >> 6);     // [0,512)
        stats_mfma<512>(bas16_1, wc16_1, grid1, sc1, st1, og, ii);
    }
}

// ---------------------------------------------------------------------------
extern "C" void kernel_launch(void* const* d_in, const int* in_sizes, int n_in,
                              void* d_out, int out_size, void* d_ws, size_t ws_size,
                              hipStream_t stream)
{
    const float* x     = (const float*)d_in[0];
    const float* grid0 = (const float*)d_in[1];
    const float* coef0 = (const float*)d_in[2];
    const float* sb0   = (const float*)d_in[3];
    const float* ssp0  = (const float*)d_in[4];
    const float* bias0 = (const float*)d_in[5];
    const float* grid1 = (const float*)d_in[6];
    const float* coef1 = (const float*)d_in[7];
    const float* sb1   = (const float*)d_in[8];
    const float* ssp1  = (const float*)d_in[9];
    const float* bias1 = (const float*)d_in[10];

    float* out = (float*)d_out;
    float* x2  = out;                 // (256,256)
    float* sc0 = out + 65536;         // (512,256)
    float* st0 = out + 196608;        // (512,256)
    float* sc1 = out + 327680;        // (256,512)
    float* st1 = out + 458752;        // (256,512)

    // Workspace (~14 MB, all disjoint): one 32B record per element.
    char* w = (char*)d_ws;
    unsigned short* wc16_0  = (unsigned short*)w; w += (size_t)131072 * 32;
    unsigned short* wc16_1  = (unsigned short*)w; w += (size_t)131072 * 32;
    unsigned short* bas16_0 = (unsigned short*)w; w += (size_t)65536 * 32;
    unsigned short* bas16_1 = (unsigned short*)w; w += (size_t)131072 * 32;

    k1_prep<<<768, 256, 0, stream>>>(
        coef0, ssp0, sb0, wc16_0, x, grid0, bas16_0);

    k2_sweep0<<<2048, 256, 0, stream>>>(
        wc16_0, bas16_0, bias0, grid1, bas16_1,
        grid0, sc0, st0, coef1, ssp1, sb1, wc16_1);

    k3_sweep1<<<1280, 256, 0, stream>>>(
        bas16_1, wc16_1, bias1, x2, grid1, sc1, st1);
}